// Round 7
// baseline (295.909 us; speedup 1.0000x reference)
//
#include <hip/hip_runtime.h>

// ---------------------------------------------------------------------------
// HeteroGNN, round 7: K=512 algebraic collapse + SPLIT back end (gather needs
// occupancy, not fusion — r6 lesson).
//   out = relu( [mean_i | mean_t | x_user] @ [Wl_i; Wl_t; W_user@(Wr_i+Wr_t)]
//               + (b_user@(Wr_i+Wr_t) + bl_i + bl_t) )        [MFMA, K=512]
// CSR: hist w/ rank-capture -> atomic-free scatter. Gather: 16 lanes/node,
// unroll-4, bf16 in/out. MFMA 16x16x32_bf16: A row=lane&15, k=(lane>>4)*8+j;
// B col=lane&15; D col=lane&15, row=(lane>>4)*4+reg  [m89-verified].
// ---------------------------------------------------------------------------

#define SCAN_CHUNK 1024

typedef __attribute__((ext_vector_type(8))) short bf16x8;
typedef __attribute__((ext_vector_type(8))) unsigned short u16x8;
typedef __attribute__((ext_vector_type(4))) float f32x4;

__device__ __forceinline__ ushort f2b(float x) {
    union { float f; unsigned u; } v; v.f = x;
    unsigned r = (v.u + 0x7FFF + ((v.u >> 16) & 1)) >> 16;   // RNE
    return (ushort)r;
}
__device__ __forceinline__ float b2f(ushort u) {
    union { unsigned u; float f; } v; v.u = (unsigned)u << 16;
    return v.f;
}

// ---- W_comb = W_user @ (Wr_i+Wr_t)  [256x128]; bias_comb = b_user@Wr_s+bl_i+bl_t ----
__global__ __launch_bounds__(256) void k_pack_w(
        const float* __restrict__ W_user, const float* __restrict__ b_user,
        const float* __restrict__ Wr_i, const float* __restrict__ Wr_t,
        const float* __restrict__ bl_i, const float* __restrict__ bl_t,
        float* __restrict__ Wcomb, float* __restrict__ bias_comb) {
    int i = blockIdx.x * 256 + threadIdx.x;      // 32768 threads
    int k = i >> 7, c = i & 127;
    float s = 0.f;
    for (int c1 = 0; c1 < 128; ++c1)
        s += W_user[k * 128 + c1] * (Wr_i[c1 * 128 + c] + Wr_t[c1 * 128 + c]);
    Wcomb[i] = s;
    if (i < 128) {
        float b = bl_i[i] + bl_t[i];
        for (int k2 = 0; k2 < 128; ++k2)
            b += b_user[k2] * (Wr_i[k2 * 128 + i] + Wr_t[k2 * 128 + i]);
        bias_comb[i] = b;
    }
}

// ---- fragment-pack Bp [K=512 x 128]: rows 0-127 Wl_i, 128-255 Wl_t, 256-511 Wcomb ----
__global__ __launch_bounds__(256) void k_pack(
        const float* __restrict__ Wl_i, const float* __restrict__ Wl_t,
        const float* __restrict__ Wcomb, ushort* __restrict__ Bp) {
    int i = blockIdx.x * 256 + threadIdx.x;      // 65536 threads
    int j = i & 7, lane = (i >> 3) & 63, cf = (i >> 9) & 7, ks = i >> 12;
    int kk = ks * 32 + (lane >> 4) * 8 + j;
    int col = cf * 16 + (lane & 15);
    float v;
    if (kk < 128)      v = Wl_i[kk * 128 + col];
    else if (kk < 256) v = Wl_t[(kk - 128) * 128 + col];
    else               v = Wcomb[(kk - 256) * 128 + col];
    Bp[i] = f2b(v);
}

// ---- fused front: [hist+rank | bf16 convert] by block range ----
__global__ __launch_bounds__(256) void k_front(
        const float* __restrict__ x_image, const float* __restrict__ x_text,
        const int* __restrict__ edge_i, const int* __restrict__ edge_t,
        ushort* __restrict__ xib, ushort* __restrict__ xtb,
        int* __restrict__ deg, int* __restrict__ rank,
        int N, int E, int nbH) {
    const int bid = blockIdx.x;
    const int tid = threadIdx.x;

    if (bid < 2 * nbH) {
        // ---- histogram + rank capture (4 edges/thread) ----
        int rel = (bid >= nbH) ? 1 : 0;
        int b = bid - rel * nbH;
        const int* eg = rel ? edge_t : edge_i;
        int* rk = rank + (size_t)rel * E;
        int* dg = deg + (size_t)rel * N;
        int e = b * 1024 + tid * 4;
        if (e + 3 < E) {
            int4 d4 = *reinterpret_cast<const int4*>(eg + E + e);
            int4 r4;
            r4.x = atomicAdd(&dg[d4.x], 1);
            r4.y = atomicAdd(&dg[d4.y], 1);
            r4.z = atomicAdd(&dg[d4.z], 1);
            r4.w = atomicAdd(&dg[d4.w], 1);
            *reinterpret_cast<int4*>(rk + e) = r4;
        } else {
            for (int j = 0; j < 4; ++j) {
                int ee = e + j;
                if (ee < E) rk[ee] = atomicAdd(&dg[eg[E + ee]], 1);
            }
        }
    } else {
        // ---- x_image/x_text f32 -> bf16 ----
        int t = (bid - 2 * nbH) * 256 + tid;
        int n8 = N * 16;
        if (t >= 2 * n8) return;
        const float* src = (t < n8) ? x_image : x_text;
        ushort* dst = (t < n8) ? xtb : xib;   // placeholder fixed below
        dst = (t < n8) ? xib : xtb;
        int i = (t < n8) ? t : t - n8;
        float4 f0 = *reinterpret_cast<const float4*>(src + (size_t)i * 8);
        float4 f1 = *reinterpret_cast<const float4*>(src + (size_t)i * 8 + 4);
        u16x8 o;
        o[0] = f2b(f0.x); o[1] = f2b(f0.y); o[2] = f2b(f0.z); o[3] = f2b(f0.w);
        o[4] = f2b(f1.x); o[5] = f2b(f1.y); o[6] = f2b(f1.z); o[7] = f2b(f1.w);
        *reinterpret_cast<u16x8*>(dst + (size_t)i * 8) = o;
    }
}

// ---- scan pass 1: per-chunk sums (over M = 2N) ----
__global__ __launch_bounds__(256) void k_scan1(const int* __restrict__ deg,
                                               int* __restrict__ bsum, int M) {
    __shared__ int sh[256];
    int base = blockIdx.x * SCAN_CHUNK;
    int t = threadIdx.x;
    int s = 0;
    #pragma unroll
    for (int j = 0; j < 4; ++j) {
        int idx = base + j * 256 + t;
        if (idx < M) s += deg[idx];
    }
    sh[t] = s; __syncthreads();
    for (int off = 128; off > 0; off >>= 1) {
        if (t < off) sh[t] += sh[t + off];
        __syncthreads();
    }
    if (t == 0) bsum[blockIdx.x] = sh[0];
}

// ---- scan pass 2: parallel exclusive scan of chunk sums (nb <= 256) ----
__global__ __launch_bounds__(256) void k_scan2(int* __restrict__ bsum, int nb,
                                               int* __restrict__ rowptr, int M, int Etot) {
    __shared__ int sh[256];
    int t = threadIdx.x;
    int v = (t < nb) ? bsum[t] : 0;
    sh[t] = v; __syncthreads();
    for (int off = 1; off < 256; off <<= 1) {
        int add = (t >= off) ? sh[t - off] : 0;
        __syncthreads();
        sh[t] += add;
        __syncthreads();
    }
    if (t < nb) bsum[t] = sh[t] - v;       // exclusive
    if (t == 0) rowptr[M] = Etot;
}

// ---- scan pass 3: intra-chunk exclusive scan -> rowptr ----
__global__ __launch_bounds__(256) void k_scan3(const int* __restrict__ deg,
                                               int* __restrict__ rowptr,
                                               const int* __restrict__ bsum, int M) {
    __shared__ int sh[256];
    int base = blockIdx.x * SCAN_CHUNK;
    int t = threadIdx.x;
    int v[4]; int s = 0;
    #pragma unroll
    for (int j = 0; j < 4; ++j) {
        int idx = base + 4 * t + j;
        v[j] = (idx < M) ? deg[idx] : 0;
        s += v[j];
    }
    sh[t] = s; __syncthreads();
    for (int off = 1; off < 256; off <<= 1) {
        int add = (t >= off) ? sh[t - off] : 0;
        __syncthreads();
        sh[t] += add;
        __syncthreads();
    }
    int run = sh[t] - s + bsum[blockIdx.x];
    #pragma unroll
    for (int j = 0; j < 4; ++j) {
        int idx = base + 4 * t + j;
        if (idx < M) { rowptr[idx] = run; run += v[j]; }
    }
}

// ---- atomic-free scatter: col[rowptr[dst] + rank[e]] = src ----
__global__ __launch_bounds__(256) void k_scatter2(
        const int* __restrict__ edge_i, const int* __restrict__ edge_t,
        const int* __restrict__ rank, const int* __restrict__ rowptr,
        int* __restrict__ col, int N, int E, int nbS) {
    const int bid = blockIdx.x;
    int rel = (bid >= nbS) ? 1 : 0;
    int b = bid - rel * nbS;
    const int* eg = rel ? edge_t : edge_i;
    const int* rk = rank + (size_t)rel * E;
    const int* rp = rowptr + (size_t)rel * N;
    int e = b * 1024 + threadIdx.x * 4;
    if (e + 3 < E) {
        int4 d4 = *reinterpret_cast<const int4*>(eg + E + e);
        int4 s4 = *reinterpret_cast<const int4*>(eg + e);
        int4 r4 = *reinterpret_cast<const int4*>(rk + e);
        __builtin_nontemporal_store(s4.x, &col[rp[d4.x] + r4.x]);
        __builtin_nontemporal_store(s4.y, &col[rp[d4.y] + r4.y]);
        __builtin_nontemporal_store(s4.z, &col[rp[d4.z] + r4.z]);
        __builtin_nontemporal_store(s4.w, &col[rp[d4.w] + r4.w]);
    } else {
        for (int j = 0; j < 4; ++j) {
            int ee = e + j;
            if (ee < E) col[rp[eg[E + ee]] + rk[ee]] = eg[ee];
        }
    }
}

// ---- gather-mean: 16 lanes/node, unroll-4, bf16 in/out, both relations ----
__global__ __launch_bounds__(256) void k_gather_mean(
        const ushort* __restrict__ xib, const ushort* __restrict__ xtb,
        const int* __restrict__ rowptr, const int* __restrict__ col,
        ushort* __restrict__ mi, ushort* __restrict__ mt, int N) {
    int t = blockIdx.x * 256 + threadIdx.x;
    int node = t >> 4, lane = t & 15;
    if (node >= N) return;
    int rel = blockIdx.y;
    const ushort* xs = rel ? xtb : xib;
    ushort* mean = rel ? mt : mi;
    int rb = rel * N + node;
    int beg = rowptr[rb], end = rowptr[rb + 1];
    float a0 = 0.f, a1 = 0.f, a2 = 0.f, a3 = 0.f,
          a4 = 0.f, a5 = 0.f, a6 = 0.f, a7 = 0.f;
    int j = beg;
    for (; j + 3 < end; j += 4) {
        int s0 = col[j], s1 = col[j + 1], s2 = col[j + 2], s3 = col[j + 3];
        u16x8 v0 = *reinterpret_cast<const u16x8*>(xs + (size_t)s0 * 128 + lane * 8);
        u16x8 v1 = *reinterpret_cast<const u16x8*>(xs + (size_t)s1 * 128 + lane * 8);
        u16x8 v2 = *reinterpret_cast<const u16x8*>(xs + (size_t)s2 * 128 + lane * 8);
        u16x8 v3 = *reinterpret_cast<const u16x8*>(xs + (size_t)s3 * 128 + lane * 8);
        a0 += (b2f(v0[0]) + b2f(v1[0])) + (b2f(v2[0]) + b2f(v3[0]));
        a1 += (b2f(v0[1]) + b2f(v1[1])) + (b2f(v2[1]) + b2f(v3[1]));
        a2 += (b2f(v0[2]) + b2f(v1[2])) + (b2f(v2[2]) + b2f(v3[2]));
        a3 += (b2f(v0[3]) + b2f(v1[3])) + (b2f(v2[3]) + b2f(v3[3]));
        a4 += (b2f(v0[4]) + b2f(v1[4])) + (b2f(v2[4]) + b2f(v3[4]));
        a5 += (b2f(v0[5]) + b2f(v1[5])) + (b2f(v2[5]) + b2f(v3[5]));
        a6 += (b2f(v0[6]) + b2f(v1[6])) + (b2f(v2[6]) + b2f(v3[6]));
        a7 += (b2f(v0[7]) + b2f(v1[7])) + (b2f(v2[7]) + b2f(v3[7]));
    }
    for (; j < end; ++j) {
        int s0 = col[j];
        u16x8 v0 = *reinterpret_cast<const u16x8*>(xs + (size_t)s0 * 128 + lane * 8);
        a0 += b2f(v0[0]); a1 += b2f(v0[1]); a2 += b2f(v0[2]); a3 += b2f(v0[3]);
        a4 += b2f(v0[4]); a5 += b2f(v0[5]); a6 += b2f(v0[6]); a7 += b2f(v0[7]);
    }
    float r = (end > beg) ? 1.0f / (float)(end - beg) : 0.0f;
    u16x8 o;
    o[0] = f2b(a0 * r); o[1] = f2b(a1 * r); o[2] = f2b(a2 * r); o[3] = f2b(a3 * r);
    o[4] = f2b(a4 * r); o[5] = f2b(a5 * r); o[6] = f2b(a6 * r); o[7] = f2b(a7 * r);
    *reinterpret_cast<u16x8*>(mean + (size_t)node * 128 + lane * 8) = o;
}

// ---- out = relu( [mi|mt|x_user](K=512) @ Bp + bias ) : MFMA ----
__global__ __launch_bounds__(256) void k_final_mfma(
        const ushort* __restrict__ mi, const ushort* __restrict__ mt,
        const float* __restrict__ x_user, const ushort* __restrict__ Bp,
        const float* __restrict__ bias, float* __restrict__ out, int N) {
    const int tid = threadIdx.x;
    const int wid = tid >> 6, lane = tid & 63;
    const int row16 = wid * 16 + (lane & 15);
    const int rA = min(blockIdx.x * 64 + row16, N - 1);
    const int kh = (lane >> 4) * 8;
    f32x4 acc[8] = {};

    #pragma unroll
    for (int ks = 0; ks < 8; ++ks) {             // means (bf16)
        const ushort* s = (ks < 4) ? mi : mt;
        bf16x8 a = *reinterpret_cast<const bf16x8*>(s + (size_t)rA * 128 + (ks & 3) * 32 + kh);
        #pragma unroll
        for (int cf = 0; cf < 8; ++cf) {
            bf16x8 bb = *reinterpret_cast<const bf16x8*>(Bp + ((ks * 8 + cf) * 64 + lane) * 8);
            acc[cf] = __builtin_amdgcn_mfma_f32_16x16x32_bf16(a, bb, acc[cf], 0, 0, 0);
        }
    }
    const float* Xr = x_user + (size_t)rA * 256;
    #pragma unroll
    for (int ks = 8; ks < 16; ++ks) {            // x_user (f32, inline cvt)
        int k0 = (ks - 8) * 32 + kh;
        float4 f0 = *reinterpret_cast<const float4*>(Xr + k0);
        float4 f1 = *reinterpret_cast<const float4*>(Xr + k0 + 4);
        bf16x8 aa;
        aa[0] = (short)f2b(f0.x); aa[1] = (short)f2b(f0.y);
        aa[2] = (short)f2b(f0.z); aa[3] = (short)f2b(f0.w);
        aa[4] = (short)f2b(f1.x); aa[5] = (short)f2b(f1.y);
        aa[6] = (short)f2b(f1.z); aa[7] = (short)f2b(f1.w);
        #pragma unroll
        for (int cf = 0; cf < 8; ++cf) {
            bf16x8 bb = *reinterpret_cast<const bf16x8*>(Bp + ((ks * 8 + cf) * 64 + lane) * 8);
            acc[cf] = __builtin_amdgcn_mfma_f32_16x16x32_bf16(aa, bb, acc[cf], 0, 0, 0);
        }
    }

    const int col0 = lane & 15;
    const int rbase = blockIdx.x * 64 + wid * 16 + (lane >> 4) * 4;
    #pragma unroll
    for (int cf = 0; cf < 8; ++cf) {
        int c = cf * 16 + col0;
        float bv = bias[c];
        #pragma unroll
        for (int r = 0; r < 4; ++r) {
            int row = rbase + r;
            if (row < N) out[(size_t)row * 128 + c] = fmaxf(acc[cf][r] + bv, 0.f);
        }
    }
}

extern "C" void kernel_launch(void* const* d_in, const int* in_sizes, int n_in,
                              void* d_out, int out_size, void* d_ws, size_t ws_size,
                              hipStream_t stream) {
    const float* x_user  = (const float*)d_in[0];
    const float* x_image = (const float*)d_in[1];
    const float* x_text  = (const float*)d_in[2];
    const int*   edge_i  = (const int*)d_in[3];
    const int*   edge_t  = (const int*)d_in[4];
    const float* W_user  = (const float*)d_in[5];
    const float* b_user  = (const float*)d_in[6];
    const float* Wl_img  = (const float*)d_in[7];
    const float* bl_img  = (const float*)d_in[8];
    const float* Wr_img  = (const float*)d_in[9];
    const float* Wl_txt  = (const float*)d_in[10];
    const float* bl_txt  = (const float*)d_in[11];
    const float* Wr_txt  = (const float*)d_in[12];

    const int N = in_sizes[0] / 256;   // 100000 nodes per type
    const int E = in_sizes[3] / 2;     // 800000 edges per relation
    const int M = 2 * N;
    const int NB = (M + SCAN_CHUNK - 1) / SCAN_CHUNK;   // <= 256

    ushort* xib    = (ushort*)d_ws;                // N*128
    ushort* xtb    = xib + (size_t)N * 128;        // N*128
    ushort* mi     = xtb + (size_t)N * 128;        // N*128
    ushort* mt     = mi  + (size_t)N * 128;        // N*128
    ushort* Bp     = mt  + (size_t)N * 128;        // 65536
    float*  Wcomb  = (float*)(Bp + 65536);         // 32768
    float*  bias   = Wcomb + 32768;                // 128
    int*    deg    = (int*)(bias + 128);           // M
    int*    rowptr = deg + M;                      // M+1 (padded to M+4)
    int*    bscan  = rowptr + (M + 4);             // NB (<=256)
    int*    rank   = bscan + 256;                  // 2E
    int*    col    = rank + (size_t)2 * E;         // 2E

    k_pack_w<<<128, 256, 0, stream>>>(W_user, b_user, Wr_img, Wr_txt,
                                      bl_img, bl_txt, Wcomb, bias);
    k_pack<<<256, 256, 0, stream>>>(Wl_img, Wl_txt, Wcomb, Bp);

    hipMemsetAsync(deg, 0, (size_t)M * sizeof(int), stream);

    const int nbH = (E + 1023) / 1024;             // hist blocks per relation
    const int nbC = (2 * N * 16 + 255) / 256;      // convert blocks
    k_front<<<2 * nbH + nbC, 256, 0, stream>>>(
        x_image, x_text, edge_i, edge_t, xib, xtb, deg, rank, N, E, nbH);

    k_scan1<<<NB, 256, 0, stream>>>(deg, bscan, M);
    k_scan2<<<1, 256, 0, stream>>>(bscan, NB, rowptr, M, 2 * E);
    k_scan3<<<NB, 256, 0, stream>>>(deg, rowptr, bscan, M);

    const int nbS = (E + 1023) / 1024;
    k_scatter2<<<2 * nbS, 256, 0, stream>>>(edge_i, edge_t, rank, rowptr, col, N, E, nbS);

    {
        dim3 g((N * 16 + 255) / 256, 2);
        k_gather_mean<<<g, 256, 0, stream>>>(xib, xtb, rowptr, col, mi, mt, N);
    }

    k_final_mfma<<<(N + 63) / 64, 256, 0, stream>>>(
        mi, mt, x_user, Bp, bias, (float*)d_out, N);
}